// Round 1
// baseline (552.236 us; speedup 1.0000x reference)
//
#include <hip/hip_runtime.h>
#include <math.h>

// ---------------------------------------------------------------------------
// TersoffAttention: E edges, T triplets, C=64 channels (== one wave).
//   pass1: a[t] = sum_c silu(cos(c*theta_t) + x[src] + x[dst]) * attn[c]
//          + segmented max over t_dst (atomicMax on order-mapped bits)
//   pass2: ex[t] = exp(a - amax[dst]); denom[dst] += ex
//   pass3: ft[dst] += xij[src] * (ex/denom[dst])
// ---------------------------------------------------------------------------

__device__ __forceinline__ unsigned int orderFloat(float f) {
    unsigned int u = __float_as_uint(f);
    // monotone map float -> uint (handles negatives)
    return (u & 0x80000000u) ? ~u : (u | 0x80000000u);
}
__device__ __forceinline__ float unorderFloat(unsigned int u) {
    return __uint_as_float((u & 0x80000000u) ? (u & 0x7FFFFFFFu) : ~u);
}

// init: rnorm4[e] = normalized r (sign dropped: it cancels in the dot),
//       amax=ordered(-inf-ish)=0, denom=0, ft=0
__global__ void ta_init(const float* __restrict__ r,
                        float4* __restrict__ rnorm4,
                        unsigned int* __restrict__ amax,
                        float* __restrict__ denom,
                        float4* __restrict__ ft4,
                        int E) {
    int i = blockIdx.x * blockDim.x + threadIdx.x;
    int nFt4 = E * 16;  // E*64 floats / 4
    if (i < nFt4) ft4[i] = make_float4(0.f, 0.f, 0.f, 0.f);
    if (i < E) {
        float rx = r[i * 3 + 0], ry = r[i * 3 + 1], rz = r[i * 3 + 2];
        float inv = rsqrtf(rx * rx + ry * ry + rz * rz);
        rnorm4[i] = make_float4(rx * inv, ry * inv, rz * inv, 0.f);
        amax[i] = 0u;      // below every ordered real float
        denom[i] = 0.f;
    }
}

// pass1: one wave per triplet, lane == channel
__global__ void ta_pass1(const float4* __restrict__ rnorm4,
                         const float* __restrict__ xij,
                         const float* __restrict__ attn,
                         const int* __restrict__ t_src,
                         const int* __restrict__ t_dst,
                         float* __restrict__ a,
                         unsigned int* __restrict__ amax,
                         int T) {
    const int lane = threadIdx.x & 63;
    const int wavesPerBlock = blockDim.x >> 6;
    const int waveId = blockIdx.x * wavesPerBlock + (threadIdx.x >> 6);
    const int nWaves = gridDim.x * wavesPerBlock;
    const float attn_c = attn[lane];
    const float flane = (float)lane;

    for (int t = waveId; t < T; t += nWaves) {
        int s = t_src[t];
        int d = t_dst[t];
        float4 rs = rnorm4[s];
        float4 rd = rnorm4[d];
        float cosj = rs.x * rd.x + rs.y * rd.y + rs.z * rd.z;
        cosj = fminf(fmaxf(cosj, -1.0f + 1e-6f), 1.0f - 1e-6f);
        float theta = acosf(cosj);
        float z = cosf(theta * flane);               // T_lane(cos theta)
        float xs = xij[s * 64 + lane];
        float xd = xij[d * 64 + lane];
        float v = z + xs + xd;
        float e = v / (1.0f + expf(-v));             // silu
        float contrib = e * attn_c;
        // wave-wide sum (64 lanes)
        #pragma unroll
        for (int o = 32; o > 0; o >>= 1) contrib += __shfl_xor(contrib, o, 64);
        if (lane == 0) {
            a[t] = contrib;
            atomicMax(&amax[d], orderFloat(contrib));
        }
    }
}

// pass2: one thread per triplet
__global__ void ta_pass2(const int* __restrict__ t_dst,
                         float* __restrict__ a_ex,      // in: a, out: ex
                         const unsigned int* __restrict__ amax,
                         float* __restrict__ denom,
                         int T) {
    int t = blockIdx.x * blockDim.x + threadIdx.x;
    int stride = gridDim.x * blockDim.x;
    for (; t < T; t += stride) {
        int d = t_dst[t];
        float m = unorderFloat(amax[d]);
        float ex = expf(a_ex[t] - m);
        a_ex[t] = ex;
        atomicAdd(&denom[d], ex);
    }
}

// pass3: one wave per triplet, lane == channel; scatter-add into ft
__global__ void ta_pass3(const float* __restrict__ xij,
                         const int* __restrict__ t_src,
                         const int* __restrict__ t_dst,
                         const float* __restrict__ ex,
                         const float* __restrict__ denom,
                         float* __restrict__ ft,
                         int T) {
    const int lane = threadIdx.x & 63;
    const int wavesPerBlock = blockDim.x >> 6;
    const int waveId = blockIdx.x * wavesPerBlock + (threadIdx.x >> 6);
    const int nWaves = gridDim.x * wavesPerBlock;

    for (int t = waveId; t < T; t += nWaves) {
        int s = t_src[t];
        int d = t_dst[t];
        float alpha = ex[t] / denom[d];
        float m = xij[s * 64 + lane] * alpha;
        atomicAdd(&ft[d * 64 + lane], m);
    }
}

extern "C" void kernel_launch(void* const* d_in, const int* in_sizes, int n_in,
                              void* d_out, int out_size, void* d_ws, size_t ws_size,
                              hipStream_t stream) {
    const float* xij   = (const float*)d_in[0];
    const float* r     = (const float*)d_in[1];
    const float* attn  = (const float*)d_in[2];
    const int*   t_src = (const int*)d_in[3];
    const int*   t_dst = (const int*)d_in[4];
    float* ft = (float*)d_out;

    const int E = in_sizes[1] / 3;   // r is [E,3]
    const int T = in_sizes[3];       // t_src is [T]

    // workspace layout (~6.4 MB for E=100k, T=1M)
    char* ws = (char*)d_ws;
    float4*       rnorm4 = (float4*)ws;                       // E * 16 B
    float*        a      = (float*)(ws + (size_t)E * 16);     // T * 4 B
    unsigned int* amax   = (unsigned int*)((char*)a + (size_t)T * 4);   // E * 4 B
    float*        denom  = (float*)((char*)amax + (size_t)E * 4);       // E * 4 B

    const int initThreads = E * 16;  // covers ft zeroing (float4) and per-edge init
    ta_init<<<(initThreads + 255) / 256, 256, 0, stream>>>(
        r, rnorm4, amax, denom, (float4*)ft, E);

    ta_pass1<<<4096, 256, 0, stream>>>(rnorm4, xij, attn, t_src, t_dst, a, amax, T);

    ta_pass2<<<2048, 256, 0, stream>>>(t_dst, a, amax, denom, T);

    ta_pass3<<<4096, 256, 0, stream>>>(xij, t_src, t_dst, a, denom, ft, T);
}

// Round 3
// 499.342 us; speedup vs baseline: 1.1059x; 1.1059x over previous
//
#include <hip/hip_runtime.h>
#include <math.h>

// ---------------------------------------------------------------------------
// TersoffAttention: E edges, T triplets, C=64 channels (== one wave).
//   pass1: a[t] = sum_c silu(cos(c*theta_t) + x[src] + x[dst]) * attn[c]
//          + segmented max over t_dst (atomicMax on order-mapped bits)
//   pass2: ex[t] = exp(a - amax[dst]); denom[dst] += ex
//   pass3: ft[dst] += xij[src] * (ex/denom[dst])
//
// R1/R2: native transcendentals. libm cosf(θ·lane) (arg up to 63π) takes the
// slow range-reduction path; v_cos_f32 (arg in revolutions, after v_fract)
// v_exp_f32 (2^x) and v_rcp_f32 are 1-3 instr each.
// R2 fix: the builtin is __builtin_amdgcn_exp2f (2^x), not _expf.
// ---------------------------------------------------------------------------

#define LOG2E 1.4426950408889634f

__device__ __forceinline__ unsigned int orderFloat(float f) {
    unsigned int u = __float_as_uint(f);
    return (u & 0x80000000u) ? ~u : (u | 0x80000000u);
}
__device__ __forceinline__ float unorderFloat(unsigned int u) {
    return __uint_as_float((u & 0x80000000u) ? (u & 0x7FFFFFFFu) : ~u);
}

__global__ void ta_init(const float* __restrict__ r,
                        float4* __restrict__ rnorm4,
                        unsigned int* __restrict__ amax,
                        float* __restrict__ denom,
                        float4* __restrict__ ft4,
                        int E) {
    int i = blockIdx.x * blockDim.x + threadIdx.x;
    int nFt4 = E * 16;  // E*64 floats / 4
    if (i < nFt4) ft4[i] = make_float4(0.f, 0.f, 0.f, 0.f);
    if (i < E) {
        float rx = r[i * 3 + 0], ry = r[i * 3 + 1], rz = r[i * 3 + 2];
        float inv = rsqrtf(rx * rx + ry * ry + rz * rz);
        rnorm4[i] = make_float4(rx * inv, ry * inv, rz * inv, 0.f);
        amax[i] = 0u;      // below every order-mapped real float
        denom[i] = 0.f;
    }
}

// pass1: one wave per triplet, lane == channel
__global__ void ta_pass1(const float4* __restrict__ rnorm4,
                         const float* __restrict__ xij,
                         const float* __restrict__ attn,
                         const int* __restrict__ t_src,
                         const int* __restrict__ t_dst,
                         float* __restrict__ a,
                         unsigned int* __restrict__ amax,
                         int T) {
    const int lane = threadIdx.x & 63;
    const int wavesPerBlock = blockDim.x >> 6;
    const int waveId = blockIdx.x * wavesPerBlock + (threadIdx.x >> 6);
    const int nWaves = gridDim.x * wavesPerBlock;
    const float attn_c = attn[lane];
    // lane * 1/(2π): per-triplet angle -> revolutions in one mul, then
    // a single v_fract + v_cos.
    const float lane_rev = (float)lane * 0.15915493667125702f;

    for (int t = waveId; t < T; t += nWaves) {
        int s = t_src[t];
        int d = t_dst[t];
        float4 rs = rnorm4[s];
        float4 rd = rnorm4[d];
        float cosj = rs.x * rd.x + rs.y * rd.y + rs.z * rd.z;
        cosj = fminf(fmaxf(cosj, -1.0f + 1e-6f), 1.0f - 1e-6f);
        float theta = acosf(cosj);               // wave-uniform, once/triplet
        float rev = theta * lane_rev;            // θ·lane in revolutions
        float z = __builtin_amdgcn_cosf(rev - floorf(rev));  // v_fract+v_cos
        float xs = xij[s * 64 + lane];
        float xd = xij[d * 64 + lane];
        float v = z + xs + xd;
        // silu: v * rcp(1 + 2^(-v*log2e))
        float ez = __builtin_amdgcn_exp2f(-v * LOG2E);
        float e = v * __builtin_amdgcn_rcpf(1.0f + ez);
        float contrib = e * attn_c;
        #pragma unroll
        for (int o = 32; o > 0; o >>= 1) contrib += __shfl_xor(contrib, o, 64);
        if (lane == 0) {
            a[t] = contrib;
            atomicMax(&amax[d], orderFloat(contrib));
        }
    }
}

// pass2: one thread per triplet
__global__ void ta_pass2(const int* __restrict__ t_dst,
                         float* __restrict__ a_ex,      // in: a, out: ex
                         const unsigned int* __restrict__ amax,
                         float* __restrict__ denom,
                         int T) {
    int t = blockIdx.x * blockDim.x + threadIdx.x;
    int stride = gridDim.x * blockDim.x;
    for (; t < T; t += stride) {
        int d = t_dst[t];
        float m = unorderFloat(amax[d]);
        float ex = __builtin_amdgcn_exp2f((a_ex[t] - m) * LOG2E);
        a_ex[t] = ex;
        atomicAdd(&denom[d], ex);
    }
}

// pass3: one wave per triplet, lane == channel; scatter-add into ft
__global__ void ta_pass3(const float* __restrict__ xij,
                         const int* __restrict__ t_src,
                         const int* __restrict__ t_dst,
                         const float* __restrict__ ex,
                         const float* __restrict__ denom,
                         float* __restrict__ ft,
                         int T) {
    const int lane = threadIdx.x & 63;
    const int wavesPerBlock = blockDim.x >> 6;
    const int waveId = blockIdx.x * wavesPerBlock + (threadIdx.x >> 6);
    const int nWaves = gridDim.x * wavesPerBlock;

    for (int t = waveId; t < T; t += nWaves) {
        int s = t_src[t];
        int d = t_dst[t];
        float alpha = ex[t] * __builtin_amdgcn_rcpf(denom[d]);
        float m = xij[s * 64 + lane] * alpha;
        atomicAdd(&ft[d * 64 + lane], m);
    }
}

extern "C" void kernel_launch(void* const* d_in, const int* in_sizes, int n_in,
                              void* d_out, int out_size, void* d_ws, size_t ws_size,
                              hipStream_t stream) {
    const float* xij   = (const float*)d_in[0];
    const float* r     = (const float*)d_in[1];
    const float* attn  = (const float*)d_in[2];
    const int*   t_src = (const int*)d_in[3];
    const int*   t_dst = (const int*)d_in[4];
    float* ft = (float*)d_out;

    const int E = in_sizes[1] / 3;   // r is [E,3]
    const int T = in_sizes[3];       // t_src is [T]

    // workspace layout (~6.4 MB for E=100k, T=1M)
    char* ws = (char*)d_ws;
    float4*       rnorm4 = (float4*)ws;                       // E * 16 B
    float*        a      = (float*)(ws + (size_t)E * 16);     // T * 4 B
    unsigned int* amax   = (unsigned int*)((char*)a + (size_t)T * 4);   // E * 4 B
    float*        denom  = (float*)((char*)amax + (size_t)E * 4);       // E * 4 B

    const int initThreads = E * 16;
    ta_init<<<(initThreads + 255) / 256, 256, 0, stream>>>(
        r, rnorm4, amax, denom, (float4*)ft, E);

    ta_pass1<<<4096, 256, 0, stream>>>(rnorm4, xij, attn, t_src, t_dst, a, amax, T);

    ta_pass2<<<2048, 256, 0, stream>>>(t_dst, a, amax, denom, T);

    ta_pass3<<<4096, 256, 0, stream>>>(xij, t_src, t_dst, a, denom, ft, T);
}

// Round 4
// 423.072 us; speedup vs baseline: 1.3053x; 1.1803x over previous
//
#include <hip/hip_runtime.h>
#include <math.h>

// ---------------------------------------------------------------------------
// TersoffAttention, CSR restructure (R3).
//   Old pass3 did 64M global f32 atomicAdds -> 214us, WRITE_SIZE=256MB
//   (atomics go memory-side). Replace with counting-sort by t_dst + a fused
//   per-edge softmax+aggregate kernel that does gather-only reads and ONE
//   plain 256B store per edge. pass2 and the amax atomics disappear.
// Kernels: init -> hist -> scan1/scan2/scan3 -> scatter -> pass1 -> reduce
// Assumes E <= 512*256 (scan2 is a single 512-thread block over block sums).
// ---------------------------------------------------------------------------

#define LOG2E 1.4426950408889634f
#define SCAN_B 256

__global__ void ta_init(const float* __restrict__ r,
                        float4* __restrict__ rnorm4,
                        int* __restrict__ rowptr,
                        int E) {
    int i = blockIdx.x * blockDim.x + threadIdx.x;
    if (i < E) {
        float rx = r[i * 3 + 0], ry = r[i * 3 + 1], rz = r[i * 3 + 2];
        float inv = rsqrtf(rx * rx + ry * ry + rz * rz);
        rnorm4[i] = make_float4(rx * inv, ry * inv, rz * inv, 0.f);
        rowptr[i] = 0;
    }
}

__global__ void ta_hist(const int* __restrict__ t_dst,
                        int* __restrict__ rowptr, int T) {
    int t = blockIdx.x * blockDim.x + threadIdx.x;
    if (t < T) atomicAdd(&rowptr[t_dst[t]], 1);
}

// in-place exclusive scan of rowptr, phase 1: per-block scan + block totals
__global__ void ta_scan1(int* __restrict__ rowptr, int* __restrict__ bsum, int E) {
    __shared__ int sm[SCAN_B];
    int i = blockIdx.x * SCAN_B + threadIdx.x;
    int v = (i < E) ? rowptr[i] : 0;
    sm[threadIdx.x] = v;
    __syncthreads();
    int x = v;
    for (int o = 1; o < SCAN_B; o <<= 1) {
        int y = (threadIdx.x >= (unsigned)o) ? sm[threadIdx.x - o] : 0;
        __syncthreads();
        x += y;
        sm[threadIdx.x] = x;
        __syncthreads();
    }
    if (i < E) rowptr[i] = x - v;                 // exclusive within block
    if (threadIdx.x == SCAN_B - 1) bsum[blockIdx.x] = x;  // block total
}

// phase 2: single-block exclusive scan of block totals (n <= 512)
__global__ void ta_scan2(int* __restrict__ bsum, int n) {
    __shared__ int sm[512];
    int tid = threadIdx.x;
    int v = (tid < n) ? bsum[tid] : 0;
    sm[tid] = v;
    __syncthreads();
    int x = v;
    for (int o = 1; o < 512; o <<= 1) {
        int y = (tid >= o) ? sm[tid - o] : 0;
        __syncthreads();
        x += y;
        sm[tid] = x;
        __syncthreads();
    }
    if (tid < n) bsum[tid] = x - v;               // exclusive
}

// phase 3: add scanned block offsets
__global__ void ta_scan3(int* __restrict__ rowptr, const int* __restrict__ bsum, int E) {
    int i = blockIdx.x * blockDim.x + threadIdx.x;
    if (i < E) rowptr[i] += bsum[i >> 8];         // 256 == SCAN_B
}

// scatter: mutates rowptr so that afterwards rowptr[e] == end-of-segment(e)
__global__ void ta_scatter(const int* __restrict__ t_dst,
                           int* __restrict__ rowptr,
                           int* __restrict__ tsorted, int T) {
    int t = blockIdx.x * blockDim.x + threadIdx.x;
    if (t < T) {
        int pos = atomicAdd(&rowptr[t_dst[t]], 1);
        tsorted[pos] = t;
    }
}

// pass1: one wave per triplet, lane == channel; writes a[t] only (no atomics)
__global__ void ta_pass1(const float4* __restrict__ rnorm4,
                         const float* __restrict__ xij,
                         const float* __restrict__ attn,
                         const int* __restrict__ t_src,
                         const int* __restrict__ t_dst,
                         float* __restrict__ a,
                         int T) {
    const int lane = threadIdx.x & 63;
    const int wavesPerBlock = blockDim.x >> 6;
    const int waveId = blockIdx.x * wavesPerBlock + (threadIdx.x >> 6);
    const int nWaves = gridDim.x * wavesPerBlock;
    const float attn_c = attn[lane];
    const float lane_rev = (float)lane * 0.15915493667125702f;  // lane/(2*pi)

    for (int t = waveId; t < T; t += nWaves) {
        int s = t_src[t];
        int d = t_dst[t];
        float4 rs = rnorm4[s];
        float4 rd = rnorm4[d];
        float cosj = rs.x * rd.x + rs.y * rd.y + rs.z * rd.z;
        cosj = fminf(fmaxf(cosj, -1.0f + 1e-6f), 1.0f - 1e-6f);
        float theta = acosf(cosj);               // wave-uniform
        float rev = theta * lane_rev;            // theta*lane in revolutions
        float z = __builtin_amdgcn_cosf(rev - floorf(rev));  // v_fract+v_cos
        float xs = xij[s * 64 + lane];
        float xd = xij[d * 64 + lane];
        float v = z + xs + xd;
        float ez = __builtin_amdgcn_exp2f(-v * LOG2E);
        float e = v * __builtin_amdgcn_rcpf(1.0f + ez);      // silu
        float contrib = e * attn_c;
        #pragma unroll
        for (int o = 32; o > 0; o >>= 1) contrib += __shfl_xor(contrib, o, 64);
        if (lane == 0) a[t] = contrib;
    }
}

// reduce: one wave per dst edge. Segment softmax + weighted gather-sum,
// single plain store. segend[e] = end of segment e (post-scatter rowptr).
__global__ void ta_reduce(const float* __restrict__ xij,
                          const int* __restrict__ t_src,
                          const float* __restrict__ a,
                          const int* __restrict__ tsorted,
                          const int* __restrict__ segend,
                          float* __restrict__ ft, int E) {
    const int lane = threadIdx.x & 63;
    const int wavesPerBlock = blockDim.x >> 6;
    const int waveId = blockIdx.x * wavesPerBlock + (threadIdx.x >> 6);
    if (waveId >= E) return;
    const int e = waveId;

    int end = segend[e];
    int start = (e == 0) ? 0 : segend[e - 1];
    int len = end - start;
    float acc = 0.f;

    if (len > 0 && len <= 64) {
        float myA = -3.402823466e38f;
        int mySrc = 0;
        if (lane < len) {
            int t = tsorted[start + lane];
            myA = a[t];
            mySrc = t_src[t];
        }
        float m = myA;
        #pragma unroll
        for (int o = 32; o > 0; o >>= 1) m = fmaxf(m, __shfl_xor(m, o, 64));
        float ex = (lane < len) ? __builtin_amdgcn_exp2f((myA - m) * LOG2E) : 0.f;
        float den = ex;
        #pragma unroll
        for (int o = 32; o > 0; o >>= 1) den += __shfl_xor(den, o, 64);
        float rden = __builtin_amdgcn_rcpf(den);
        for (int j = 0; j < len; ++j) {
            float alpha = __shfl(ex, j, 64) * rden;
            int s = __shfl(mySrc, j, 64);
            acc += alpha * xij[s * 64 + lane];
        }
    } else if (len > 64) {
        // rare generic path (len > 64): two extra sweeps over the segment
        float m = -3.402823466e38f;
        for (int b = start + lane; b < end; b += 64) m = fmaxf(m, a[tsorted[b]]);
        #pragma unroll
        for (int o = 32; o > 0; o >>= 1) m = fmaxf(m, __shfl_xor(m, o, 64));
        float den = 0.f;
        for (int b = start + lane; b < end; b += 64)
            den += __builtin_amdgcn_exp2f((a[tsorted[b]] - m) * LOG2E);
        #pragma unroll
        for (int o = 32; o > 0; o >>= 1) den += __shfl_xor(den, o, 64);
        float rden = __builtin_amdgcn_rcpf(den);
        for (int j = start; j < end; ++j) {
            int t = tsorted[j];  // uniform -> broadcast load
            float alpha = __builtin_amdgcn_exp2f((a[t] - m) * LOG2E) * rden;
            acc += alpha * xij[t_src[t] * 64 + lane];
        }
    }
    ft[e * 64 + lane] = acc;   // empty segment -> zeros (matches reference)
}

extern "C" void kernel_launch(void* const* d_in, const int* in_sizes, int n_in,
                              void* d_out, int out_size, void* d_ws, size_t ws_size,
                              hipStream_t stream) {
    const float* xij   = (const float*)d_in[0];
    const float* r     = (const float*)d_in[1];
    const float* attn  = (const float*)d_in[2];
    const int*   t_src = (const int*)d_in[3];
    const int*   t_dst = (const int*)d_in[4];
    float* ft = (float*)d_out;

    const int E = in_sizes[1] / 3;   // r is [E,3]
    const int T = in_sizes[3];       // t_src is [T]

    // workspace layout (~9.7 MB for E=100k, T=1M)
    char* ws = (char*)d_ws;
    float4* rnorm4  = (float4*)ws;                                   // E*16 B
    float*  a       = (float*)(ws + (size_t)E * 16);                 // T*4 B
    int*    tsorted = (int*)((char*)a + (size_t)T * 4);              // T*4 B
    int*    rowptr  = (int*)((char*)tsorted + (size_t)T * 4);        // E*4 B
    int*    bsum    = (int*)((char*)rowptr + (size_t)E * 4);         // <=512*4 B

    const int nScanBlocks = (E + SCAN_B - 1) / SCAN_B;   // 391 for E=100k

    ta_init<<<(E + 255) / 256, 256, 0, stream>>>(r, rnorm4, rowptr, E);
    ta_hist<<<(T + 255) / 256, 256, 0, stream>>>(t_dst, rowptr, T);
    ta_scan1<<<nScanBlocks, SCAN_B, 0, stream>>>(rowptr, bsum, E);
    ta_scan2<<<1, 512, 0, stream>>>(bsum, nScanBlocks);
    ta_scan3<<<nScanBlocks, SCAN_B, 0, stream>>>(rowptr, bsum, E);
    ta_scatter<<<(T + 255) / 256, 256, 0, stream>>>(t_dst, rowptr, tsorted, T);
    ta_pass1<<<4096, 256, 0, stream>>>(rnorm4, xij, attn, t_src, t_dst, a, T);
    ta_reduce<<<(E + 3) / 4, 256, 0, stream>>>(xij, t_src, a, tsorted, rowptr, ft, E);
}

// Round 5
// 356.498 us; speedup vs baseline: 1.5491x; 1.1867x over previous
//
#include <hip/hip_runtime.h>
#include <math.h>

// ---------------------------------------------------------------------------
// TersoffAttention (R4): CSR sort + subwave-8 pass1.
//   pass1 was VALU-bound at ~135 wave-instr/triplet with lane=channel (wave-
//   uniform acosf + 6-step reduce paid per triplet). Now 8 lanes/triplet,
//   8 triplets/wave, iterating in tsorted order: acosf amortizes 8x, reduce
//   is 3 shuffle steps, xij[d]/rnorm4[d] gathers hit L1 (sorted d-locality),
//   and a[] is written/read coalesced in sorted positions.
// Kernels: init -> hist -> scan1/scan2/scan3 -> scatter -> pass1 -> reduce
// ---------------------------------------------------------------------------

#define LOG2E 1.4426950408889634f
#define SCAN_B 256

__global__ void ta_init(const float* __restrict__ r,
                        float4* __restrict__ rnorm4,
                        int* __restrict__ rowptr,
                        int E) {
    int i = blockIdx.x * blockDim.x + threadIdx.x;
    if (i < E) {
        float rx = r[i * 3 + 0], ry = r[i * 3 + 1], rz = r[i * 3 + 2];
        float inv = rsqrtf(rx * rx + ry * ry + rz * rz);
        rnorm4[i] = make_float4(rx * inv, ry * inv, rz * inv, 0.f);
        rowptr[i] = 0;
    }
}

__global__ void ta_hist(const int* __restrict__ t_dst,
                        int* __restrict__ rowptr, int T) {
    int t = blockIdx.x * blockDim.x + threadIdx.x;
    if (t < T) atomicAdd(&rowptr[t_dst[t]], 1);
}

__global__ void ta_scan1(int* __restrict__ rowptr, int* __restrict__ bsum, int E) {
    __shared__ int sm[SCAN_B];
    int i = blockIdx.x * SCAN_B + threadIdx.x;
    int v = (i < E) ? rowptr[i] : 0;
    sm[threadIdx.x] = v;
    __syncthreads();
    int x = v;
    for (int o = 1; o < SCAN_B; o <<= 1) {
        int y = (threadIdx.x >= (unsigned)o) ? sm[threadIdx.x - o] : 0;
        __syncthreads();
        x += y;
        sm[threadIdx.x] = x;
        __syncthreads();
    }
    if (i < E) rowptr[i] = x - v;
    if (threadIdx.x == SCAN_B - 1) bsum[blockIdx.x] = x;
}

__global__ void ta_scan2(int* __restrict__ bsum, int n) {
    __shared__ int sm[512];
    int tid = threadIdx.x;
    int v = (tid < n) ? bsum[tid] : 0;
    sm[tid] = v;
    __syncthreads();
    int x = v;
    for (int o = 1; o < 512; o <<= 1) {
        int y = (tid >= o) ? sm[tid - o] : 0;
        __syncthreads();
        x += y;
        sm[tid] = x;
        __syncthreads();
    }
    if (tid < n) bsum[tid] = x - v;
}

__global__ void ta_scan3(int* __restrict__ rowptr, const int* __restrict__ bsum, int E) {
    int i = blockIdx.x * blockDim.x + threadIdx.x;
    if (i < E) rowptr[i] += bsum[i >> 8];
}

// scatter: afterwards rowptr[e] == end-of-segment(e)
__global__ void ta_scatter(const int* __restrict__ t_dst,
                           int* __restrict__ rowptr,
                           int* __restrict__ tsorted, int T) {
    int t = blockIdx.x * blockDim.x + threadIdx.x;
    if (t < T) {
        int pos = atomicAdd(&rowptr[t_dst[t]], 1);
        tsorted[pos] = t;
    }
}

// pass1: 8 lanes per triplet (sub = channel-octet, grp = triplet slot),
// iterating sorted order; writes a[] in sorted positions, coalesced.
__global__ void ta_pass1(const float4* __restrict__ rnorm4,
                         const float* __restrict__ xij,
                         const float* __restrict__ attn,
                         const int* __restrict__ t_src,
                         const int* __restrict__ t_dst,
                         const int* __restrict__ tsorted,
                         float* __restrict__ a,
                         int T) {
    const int lane = threadIdx.x & 63;
    const int sub  = lane & 7;        // which channel octet (0..7)
    const int grp  = lane >> 3;       // which triplet slot (0..7)
    const int wavesPerBlock = blockDim.x >> 6;
    const int waveId = blockIdx.x * wavesPerBlock + (threadIdx.x >> 6);
    const int nWaves = gridDim.x * wavesPerBlock;
    const int c0 = sub * 8;
    const float inv2pi = 0.15915493667125702f;

    float atv[8];
    *(float4*)(&atv[0]) = *(const float4*)(attn + c0);
    *(float4*)(&atv[4]) = *(const float4*)(attn + c0 + 4);
    const float fc0 = (float)c0;

    for (int base = waveId * 8; base < T; base += nWaves * 8) {
        int i  = base + grp;
        int ic = (i < T) ? i : (T - 1);
        int t  = tsorted[ic];
        int s  = t_src[t];
        int d  = t_dst[t];
        float4 rs = rnorm4[s];
        float4 rd = rnorm4[d];
        float cosj = rs.x * rd.x + rs.y * rd.y + rs.z * rd.z;
        cosj = fminf(fmaxf(cosj, -1.0f + 1e-6f), 1.0f - 1e-6f);
        float th2p = acosf(cosj) * inv2pi;    // theta in revolutions

        const float* xs = xij + (size_t)s * 64 + c0;
        const float* xd = xij + (size_t)d * 64 + c0;
        float xsv[8], xdv[8];
        *(float4*)(&xsv[0]) = *(const float4*)(xs);
        *(float4*)(&xsv[4]) = *(const float4*)(xs + 4);
        *(float4*)(&xdv[0]) = *(const float4*)(xd);
        *(float4*)(&xdv[4]) = *(const float4*)(xd + 4);

        float part = 0.f;
        #pragma unroll
        for (int k = 0; k < 8; ++k) {
            float rev = th2p * (fc0 + (float)k);
            float z = __builtin_amdgcn_cosf(rev - floorf(rev));
            float v = z + xsv[k] + xdv[k];
            float ez = __builtin_amdgcn_exp2f(-v * LOG2E);
            float e = v * __builtin_amdgcn_rcpf(1.0f + ez);   // silu
            part = fmaf(e, atv[k], part);
        }
        // reduce across the 8 lanes of the group
        part += __shfl_xor(part, 1, 64);
        part += __shfl_xor(part, 2, 64);
        part += __shfl_xor(part, 4, 64);
        // group g's result lives at lane g*8; move to lane g, store coalesced
        float aval = __shfl(part, (lane & 7) * 8, 64);
        if (lane < 8) {
            int ii = base + lane;
            if (ii < T) a[ii] = aval;
        }
    }
}

// reduce: one wave per dst edge; a[] is already in sorted order (coalesced).
__global__ void ta_reduce(const float* __restrict__ xij,
                          const int* __restrict__ t_src,
                          const float* __restrict__ a,
                          const int* __restrict__ tsorted,
                          const int* __restrict__ segend,
                          float* __restrict__ ft, int E) {
    const int lane = threadIdx.x & 63;
    const int wavesPerBlock = blockDim.x >> 6;
    const int waveId = blockIdx.x * wavesPerBlock + (threadIdx.x >> 6);
    if (waveId >= E) return;
    const int e = waveId;

    int end = segend[e];
    int start = (e == 0) ? 0 : segend[e - 1];
    int len = end - start;
    float acc = 0.f;

    if (len > 0 && len <= 64) {
        float myA = -3.402823466e38f;
        int mySrc = 0;
        if (lane < len) {
            myA = a[start + lane];                 // coalesced
            mySrc = t_src[tsorted[start + lane]];
        }
        float m = myA;
        #pragma unroll
        for (int o = 32; o > 0; o >>= 1) m = fmaxf(m, __shfl_xor(m, o, 64));
        float ex = (lane < len) ? __builtin_amdgcn_exp2f((myA - m) * LOG2E) : 0.f;
        float den = ex;
        #pragma unroll
        for (int o = 32; o > 0; o >>= 1) den += __shfl_xor(den, o, 64);
        float rden = __builtin_amdgcn_rcpf(den);
        for (int j = 0; j < len; ++j) {
            float alpha = __shfl(ex, j, 64) * rden;
            int s = __shfl(mySrc, j, 64);
            acc += alpha * xij[s * 64 + lane];
        }
    } else if (len > 64) {
        float m = -3.402823466e38f;
        for (int b = start + lane; b < end; b += 64) m = fmaxf(m, a[b]);
        #pragma unroll
        for (int o = 32; o > 0; o >>= 1) m = fmaxf(m, __shfl_xor(m, o, 64));
        float den = 0.f;
        for (int b = start + lane; b < end; b += 64)
            den += __builtin_amdgcn_exp2f((a[b] - m) * LOG2E);
        #pragma unroll
        for (int o = 32; o > 0; o >>= 1) den += __shfl_xor(den, o, 64);
        float rden = __builtin_amdgcn_rcpf(den);
        for (int j = start; j < end; ++j) {
            float alpha = __builtin_amdgcn_exp2f((a[j] - m) * LOG2E) * rden;
            int t = tsorted[j];   // uniform -> broadcast load
            acc += alpha * xij[t_src[t] * 64 + lane];
        }
    }
    ft[e * 64 + lane] = acc;
}

extern "C" void kernel_launch(void* const* d_in, const int* in_sizes, int n_in,
                              void* d_out, int out_size, void* d_ws, size_t ws_size,
                              hipStream_t stream) {
    const float* xij   = (const float*)d_in[0];
    const float* r     = (const float*)d_in[1];
    const float* attn  = (const float*)d_in[2];
    const int*   t_src = (const int*)d_in[3];
    const int*   t_dst = (const int*)d_in[4];
    float* ft = (float*)d_out;

    const int E = in_sizes[1] / 3;   // r is [E,3]
    const int T = in_sizes[3];       // t_src is [T]

    // workspace layout (~9.7 MB for E=100k, T=1M)
    char* ws = (char*)d_ws;
    float4* rnorm4  = (float4*)ws;                                   // E*16 B
    float*  a       = (float*)(ws + (size_t)E * 16);                 // T*4 B
    int*    tsorted = (int*)((char*)a + (size_t)T * 4);              // T*4 B
    int*    rowptr  = (int*)((char*)tsorted + (size_t)T * 4);        // E*4 B
    int*    bsum    = (int*)((char*)rowptr + (size_t)E * 4);         // <=512*4 B

    const int nScanBlocks = (E + SCAN_B - 1) / SCAN_B;   // 391 for E=100k

    ta_init<<<(E + 255) / 256, 256, 0, stream>>>(r, rnorm4, rowptr, E);
    ta_hist<<<(T + 255) / 256, 256, 0, stream>>>(t_dst, rowptr, T);
    ta_scan1<<<nScanBlocks, SCAN_B, 0, stream>>>(rowptr, bsum, E);
    ta_scan2<<<1, 512, 0, stream>>>(bsum, nScanBlocks);
    ta_scan3<<<nScanBlocks, SCAN_B, 0, stream>>>(rowptr, bsum, E);
    ta_scatter<<<(T + 255) / 256, 256, 0, stream>>>(t_dst, rowptr, tsorted, T);
    ta_pass1<<<4096, 256, 0, stream>>>(rnorm4, xij, attn, t_src, t_dst, tsorted, a, T);
    ta_reduce<<<(E + 3) / 4, 256, 0, stream>>>(xij, t_src, a, tsorted, rowptr, ft, E);
}

// Round 6
// 308.339 us; speedup vs baseline: 1.7910x; 1.1562x over previous
//
#include <hip/hip_runtime.h>
#include <math.h>

// ---------------------------------------------------------------------------
// TersoffAttention (R5): CSR sort + single fused per-segment kernel.
//   R4's pass1 (81us) re-gathered xij[d] per triplet and ta_reduce re-gathered
//   xij[s] (256MB) + a[]. Fused wave-per-segment kernel:
//     phase A (lane=triplet): acosf for <=64 triplets at full lane width
//     phase B (lane=channel): cos/silu/attn-dot + butterfly reduce, online
//       softmax (m, den, acc rescale), xij[s] gathered ONCE per triplet,
//       xij[d] loaded once per segment (d == e == waveId).
//   ssorted[] stores t_src[t] directly (scatter does the t->src lookup where
//   t_src reads are coalesced), killing the tsorted->t_src double gather.
// Kernels: init -> hist -> scan1/scan2/scan3 -> scatter -> fused
// ---------------------------------------------------------------------------

#define LOG2E 1.4426950408889634f
#define SCAN_B 256

__global__ void ta_init(const float* __restrict__ r,
                        float4* __restrict__ rnorm4,
                        int* __restrict__ rowptr,
                        int E) {
    int i = blockIdx.x * blockDim.x + threadIdx.x;
    if (i < E) {
        float rx = r[i * 3 + 0], ry = r[i * 3 + 1], rz = r[i * 3 + 2];
        float inv = rsqrtf(rx * rx + ry * ry + rz * rz);
        rnorm4[i] = make_float4(rx * inv, ry * inv, rz * inv, 0.f);
        rowptr[i] = 0;
    }
}

__global__ void ta_hist(const int* __restrict__ t_dst,
                        int* __restrict__ rowptr, int T) {
    int t = blockIdx.x * blockDim.x + threadIdx.x;
    if (t < T) atomicAdd(&rowptr[t_dst[t]], 1);
}

__global__ void ta_scan1(int* __restrict__ rowptr, int* __restrict__ bsum, int E) {
    __shared__ int sm[SCAN_B];
    int i = blockIdx.x * SCAN_B + threadIdx.x;
    int v = (i < E) ? rowptr[i] : 0;
    sm[threadIdx.x] = v;
    __syncthreads();
    int x = v;
    for (int o = 1; o < SCAN_B; o <<= 1) {
        int y = (threadIdx.x >= (unsigned)o) ? sm[threadIdx.x - o] : 0;
        __syncthreads();
        x += y;
        sm[threadIdx.x] = x;
        __syncthreads();
    }
    if (i < E) rowptr[i] = x - v;
    if (threadIdx.x == SCAN_B - 1) bsum[blockIdx.x] = x;
}

__global__ void ta_scan2(int* __restrict__ bsum, int n) {
    __shared__ int sm[512];
    int tid = threadIdx.x;
    int v = (tid < n) ? bsum[tid] : 0;
    sm[tid] = v;
    __syncthreads();
    int x = v;
    for (int o = 1; o < 512; o <<= 1) {
        int y = (tid >= o) ? sm[tid - o] : 0;
        __syncthreads();
        x += y;
        sm[tid] = x;
        __syncthreads();
    }
    if (tid < n) bsum[tid] = x - v;
}

__global__ void ta_scan3(int* __restrict__ rowptr, const int* __restrict__ bsum, int E) {
    int i = blockIdx.x * blockDim.x + threadIdx.x;
    if (i < E) rowptr[i] += bsum[i >> 8];
}

// scatter: ssorted[pos] = t_src[t]; afterwards rowptr[e] == end-of-segment(e)
__global__ void ta_scatter(const int* __restrict__ t_dst,
                           const int* __restrict__ t_src,
                           int* __restrict__ rowptr,
                           int* __restrict__ ssorted, int T) {
    int t = blockIdx.x * blockDim.x + threadIdx.x;
    if (t < T) {
        int pos = atomicAdd(&rowptr[t_dst[t]], 1);
        ssorted[pos] = t_src[t];
    }
}

// fused: one wave per dst edge e (== d). Two-phase per 64-triplet chunk:
//   A) lane=triplet: acosf at full width  B) lane=channel: silu+dot+online SM
__global__ void ta_fused(const float* __restrict__ xij,
                         const float* __restrict__ attn,
                         const float4* __restrict__ rnorm4,
                         const int* __restrict__ ssorted,
                         const int* __restrict__ segend,
                         float* __restrict__ ft, int E) {
    const int lane = threadIdx.x & 63;
    const int waveId = blockIdx.x * (blockDim.x >> 6) + (threadIdx.x >> 6);
    if (waveId >= E) return;
    const int e = waveId;

    int end = segend[e];
    int start = (e == 0) ? 0 : segend[e - 1];

    const float attn_c = attn[lane];
    const float flane = (float)lane;
    const float xd = xij[(size_t)e * 64 + lane];   // d == e, once per segment
    const float4 rd = rnorm4[e];

    float m = -3.402823466e38f, den = 0.f, acc = 0.f;

    for (int c0 = start; c0 < end; c0 += 64) {
        int cl = end - c0; if (cl > 64) cl = 64;
        // ---- phase A: lane = triplet slot ----
        int idx = c0 + lane; if (idx >= end) idx = end - 1;  // clamp, unused lanes
        int sv = ssorted[idx];                     // coalesced
        float4 rs = rnorm4[sv];                    // gather, full lane width
        float cosj = rs.x * rd.x + rs.y * rd.y + rs.z * rd.z;
        cosj = fminf(fmaxf(cosj, -1.0f + 1e-6f), 1.0f - 1e-6f);
        float th2p = acosf(cosj) * 0.15915493667125702f;   // theta/(2*pi)

        // ---- phase B: lane = channel ----
        for (int j = 0; j < cl; ++j) {
            float th = __shfl(th2p, j, 64);
            int   s  = __shfl(sv, j, 64);
            float xs = xij[(size_t)s * 64 + lane];          // gathered ONCE
            float rev = th * flane;
            float z = __builtin_amdgcn_cosf(rev - floorf(rev));
            float v = z + xs + xd;
            float ez = __builtin_amdgcn_exp2f(-v * LOG2E);
            float sl = v * __builtin_amdgcn_rcpf(1.0f + ez);   // silu
            float contrib = sl * attn_c;
            #pragma unroll
            for (int o = 32; o > 0; o >>= 1) contrib += __shfl_xor(contrib, o, 64);
            // online softmax update (all wave-uniform except acc/xs)
            float mn = fmaxf(m, contrib);
            float scale = __builtin_amdgcn_exp2f((m - mn) * LOG2E);
            float p     = __builtin_amdgcn_exp2f((contrib - mn) * LOG2E);
            den = den * scale + p;
            acc = acc * scale + p * xs;
            m = mn;
        }
    }
    float out = (end > start) ? acc * __builtin_amdgcn_rcpf(den) : 0.f;
    ft[(size_t)e * 64 + lane] = out;
}

extern "C" void kernel_launch(void* const* d_in, const int* in_sizes, int n_in,
                              void* d_out, int out_size, void* d_ws, size_t ws_size,
                              hipStream_t stream) {
    const float* xij   = (const float*)d_in[0];
    const float* r     = (const float*)d_in[1];
    const float* attn  = (const float*)d_in[2];
    const int*   t_src = (const int*)d_in[3];
    const int*   t_dst = (const int*)d_in[4];
    float* ft = (float*)d_out;

    const int E = in_sizes[1] / 3;   // r is [E,3]
    const int T = in_sizes[3];       // t_src is [T]

    // workspace layout (~6 MB for E=100k, T=1M)
    char* ws = (char*)d_ws;
    float4* rnorm4  = (float4*)ws;                                   // E*16 B
    int*    ssorted = (int*)(ws + (size_t)E * 16);                   // T*4 B
    int*    rowptr  = (int*)((char*)ssorted + (size_t)T * 4);        // E*4 B
    int*    bsum    = (int*)((char*)rowptr + (size_t)E * 4);         // <=512*4 B

    const int nScanBlocks = (E + SCAN_B - 1) / SCAN_B;   // 391 for E=100k

    ta_init<<<(E + 255) / 256, 256, 0, stream>>>(r, rnorm4, rowptr, E);
    ta_hist<<<(T + 255) / 256, 256, 0, stream>>>(t_dst, rowptr, T);
    ta_scan1<<<nScanBlocks, SCAN_B, 0, stream>>>(rowptr, bsum, E);
    ta_scan2<<<1, 512, 0, stream>>>(bsum, nScanBlocks);
    ta_scan3<<<nScanBlocks, SCAN_B, 0, stream>>>(rowptr, bsum, E);
    ta_scatter<<<(T + 255) / 256, 256, 0, stream>>>(t_dst, t_src, rowptr, ssorted, T);
    ta_fused<<<(E + 3) / 4, 256, 0, stream>>>(xij, attn, rnorm4, ssorted, rowptr, ft, E);
}